// Round 1
// baseline (3073.356 us; speedup 1.0000x reference)
//
#include <hip/hip_runtime.h>
#include <math.h>

#define BB 8
#define CC 256
#define NN 2048

static const size_t CN  = (size_t)CC * NN;   // 524288 elements per [C,N] slab
static const size_t XBS = 3 * CN;            // per-batch stride of input x [B,3,C,N]

typedef unsigned short u16;

__device__ __forceinline__ float bf2f(u16 v) {
    union { unsigned int u; float f; } t; t.u = ((unsigned int)v) << 16; return t.f;
}
__device__ __forceinline__ u16 f2bf(float f) {
    union { float f; unsigned int u; } t; t.f = f;
    unsigned int r = (t.u + 0x7fffu + ((t.u >> 16) & 1u)) >> 16;
    return (u16)r;
}
__device__ __forceinline__ float sigf(float x) { return 1.0f / (1.0f + expf(-x)); }

// ---------------------------------------------------------------------------
// conv1x1: out[b,c,n] = sum_k W[c,k] * X[b,k,n]  (64x64 tile, 4x4 microtile)
// MODE 0: plain (Q/K)
// MODE 1: + bias[c] (V)
// MODE 2: X := Xsrc - XR on the fly; out = Xsrc + relu(sum + bias)  (T stage)
// ---------------------------------------------------------------------------
template<int MODE>
__global__ __launch_bounds__(256) void conv1x1_kernel(
    const float* __restrict__ W,     // [CC,CC]
    const float* __restrict__ X,     // batch stride xbs
    long xbs,
    const float* __restrict__ XR,    // MODE2 only: [B,C,N], batch stride CN
    const float* __restrict__ bias,  // MODE1/2: [CC]
    float* __restrict__ out,         // batch stride obs
    long obs)
{
    const int b   = blockIdx.z;
    const int c0  = blockIdx.y * 64;
    const int n0  = blockIdx.x * 64;
    const int tid = threadIdx.x;
    const float* Xb  = X + (size_t)b * xbs;
    const float* XRb = (MODE == 2) ? (XR + (size_t)b * CN) : nullptr;

    __shared__ float Ws[64][68];   // Ws[k][c]  (transposed W tile)
    __shared__ float Xs[64][68];   // Xs[k][n]

    float acc[4][4] = {};
    const int ty = tid >> 4, tx = tid & 15;

    for (int k0 = 0; k0 < CC; k0 += 64) {
        {   // W tile: coalesced along k
            const int k  = tid & 63;
            const int cb = tid >> 6;
            #pragma unroll
            for (int rep = 0; rep < 16; rep++) {
                const int c = cb * 16 + rep;
                Ws[k][c] = W[(size_t)(c0 + c) * CC + (k0 + k)];
            }
        }
        {   // X tile: coalesced along n
            const int n4 = (tid & 15) * 4;
            const int kb = tid >> 4;
            #pragma unroll
            for (int rep = 0; rep < 4; rep++) {
                const int k = kb + rep * 16;
                const size_t goff = (size_t)(k0 + k) * NN + n0 + n4;
                float4 xv = *(const float4*)&Xb[goff];
                if (MODE == 2) {
                    const float4 rv = *(const float4*)&XRb[goff];
                    xv.x -= rv.x; xv.y -= rv.y; xv.z -= rv.z; xv.w -= rv.w;
                }
                *(float4*)&Xs[k][n4] = xv;
            }
        }
        __syncthreads();
        #pragma unroll 16
        for (int kk = 0; kk < 64; kk++) {
            float av[4], bv[4];
            *(float4*)av = *(const float4*)&Ws[kk][ty * 4];
            *(float4*)bv = *(const float4*)&Xs[kk][tx * 4];
            #pragma unroll
            for (int i = 0; i < 4; i++)
                #pragma unroll
                for (int j = 0; j < 4; j++)
                    acc[i][j] = fmaf(av[i], bv[j], acc[i][j]);
        }
        __syncthreads();
    }

    float* Ob = out + (size_t)b * obs;
    if (MODE == 0 || MODE == 1) {
        #pragma unroll
        for (int i = 0; i < 4; i++) {
            const int c = c0 + ty * 4 + i;
            const float bi = (MODE == 1) ? bias[c] : 0.0f;
            float4 o;
            o.x = acc[i][0] + bi; o.y = acc[i][1] + bi;
            o.z = acc[i][2] + bi; o.w = acc[i][3] + bi;
            *(float4*)&Ob[(size_t)c * NN + n0 + tx * 4] = o;
        }
    } else {
        #pragma unroll
        for (int i = 0; i < 4; i++) {
            const int c = c0 + ty * 4 + i;
            const float bi = bias[c];
            const float4 xv = *(const float4*)&Xb[(size_t)c * NN + n0 + tx * 4];
            float4 o;
            o.x = xv.x + fmaxf(acc[i][0] + bi, 0.0f);
            o.y = xv.y + fmaxf(acc[i][1] + bi, 0.0f);
            o.z = xv.z + fmaxf(acc[i][2] + bi, 0.0f);
            o.w = xv.w + fmaxf(acc[i][3] + bi, 0.0f);
            *(float4*)&Ob[(size_t)c * NN + n0 + tx * 4] = o;
        }
    }
}

// ---------------------------------------------------------------------------
// attn_kernel: 8 rows of logits L[n,m] = sum_c Q[c,n]*K[c,m]; row softmax;
// S (bf16) write; per-block partial column sums (deterministic, no atomics).
// ---------------------------------------------------------------------------
__global__ __launch_bounds__(256) void attn_kernel(
    const float* __restrict__ Q,   // [B,C,N]
    const float* __restrict__ K,   // [B,C,N]
    u16* __restrict__ S,           // [B,N,N] bf16
    float* __restrict__ cspart)    // [B, N/8, N]
{
    const int b   = blockIdx.y;
    const int n0  = blockIdx.x * 8;
    const int tid = threadIdx.x;

    __shared__ float Qs[256][8];      // Qs[c][r]
    __shared__ float Ls[8][2048];
    __shared__ float rs[8];

    {   // stage 8 Q rows (transposed into [c][r])
        const size_t base = ((size_t)b * CC + tid) * NN + n0;
        const float4 q0 = *(const float4*)&Q[base];
        const float4 q1 = *(const float4*)&Q[base + 4];
        *(float4*)&Qs[tid][0] = q0;
        *(float4*)&Qs[tid][4] = q1;
    }
    __syncthreads();

    float4 acc[8][2];
    #pragma unroll
    for (int r = 0; r < 8; r++)
        #pragma unroll
        for (int j = 0; j < 2; j++) { acc[r][j].x = 0.f; acc[r][j].y = 0.f; acc[r][j].z = 0.f; acc[r][j].w = 0.f; }

    const float* Kb = K + (size_t)b * CN;
    const int m0 = tid * 4;    // lane owns m0..m0+3 and m0+1024..+1027

    #pragma unroll 4
    for (int c = 0; c < CC; c++) {
        float qv[8];
        *(float4*)&qv[0] = *(const float4*)&Qs[c][0];   // LDS broadcast
        *(float4*)&qv[4] = *(const float4*)&Qs[c][4];
        #pragma unroll
        for (int j = 0; j < 2; j++) {
            const float4 kv = *(const float4*)&Kb[(size_t)c * NN + j * 1024 + m0];
            #pragma unroll
            for (int r = 0; r < 8; r++) {
                acc[r][j].x = fmaf(qv[r], kv.x, acc[r][j].x);
                acc[r][j].y = fmaf(qv[r], kv.y, acc[r][j].y);
                acc[r][j].z = fmaf(qv[r], kv.z, acc[r][j].z);
                acc[r][j].w = fmaf(qv[r], kv.w, acc[r][j].w);
            }
        }
    }

    #pragma unroll
    for (int r = 0; r < 8; r++) {
        *(float4*)&Ls[r][m0]        = acc[r][0];
        *(float4*)&Ls[r][m0 + 1024] = acc[r][1];
    }
    __syncthreads();

    // wave-per-row softmax: wave w handles rows 2w, 2w+1
    const int w = tid >> 6, lane = tid & 63;
    #pragma unroll
    for (int rr = 0; rr < 2; rr++) {
        const int r = w * 2 + rr;
        float mx = -1e30f;
        for (int k = 0; k < 32; k++) mx = fmaxf(mx, Ls[r][lane + k * 64]);
        #pragma unroll
        for (int o = 32; o; o >>= 1) mx = fmaxf(mx, __shfl_xor(mx, o));
        float sum = 0.0f;
        for (int k = 0; k < 32; k++) {
            const float e = expf(Ls[r][lane + k * 64] - mx);
            Ls[r][lane + k * 64] = e;
            sum += e;
        }
        #pragma unroll
        for (int o = 32; o; o >>= 1) sum += __shfl_xor(sum, o);
        const float rinv = 1.0f / sum;
        if (lane == 0) rs[r] = rinv;
        u16* Srow = S + ((size_t)b * NN + n0 + r) * NN;
        for (int k = 0; k < 32; k++) {
            const int m = lane + k * 64;
            Srow[m] = f2bf(Ls[r][m] * rinv);
        }
    }
    __syncthreads();

    float rsv[8];
    #pragma unroll
    for (int r = 0; r < 8; r++) rsv[r] = rs[r];
    float* cp = cspart + ((size_t)b * (NN / 8) + blockIdx.x) * NN;
    #pragma unroll
    for (int k = 0; k < 8; k++) {
        const int m = tid + k * 256;
        float s = 0.0f;
        #pragma unroll
        for (int r = 0; r < 8; r++) s = fmaf(Ls[r][m], rsv[r], s);
        cp[m] = s;
    }
}

// ---------------------------------------------------------------------------
// csum: colsum[b,m] = sum_g cspart[b,g,m]
// ---------------------------------------------------------------------------
__global__ __launch_bounds__(256) void csum_kernel(const float* __restrict__ cspart,
                                                   float* __restrict__ colsum)
{
    const int b  = blockIdx.y;
    const int ml = threadIdx.x & 63;
    const int m  = blockIdx.x * 64 + ml;
    const int g0 = threadIdx.x >> 6;
    float s = 0.0f;
    for (int g = g0; g < 256; g += 4)
        s += cspart[((size_t)b * 256 + g) * NN + m];
    __shared__ float red[4][64];
    red[g0][ml] = s;
    __syncthreads();
    if (threadIdx.x < 64) {
        const float t = red[0][threadIdx.x] + red[1][threadIdx.x] +
                        red[2][threadIdx.x] + red[3][threadIdx.x];
        colsum[(size_t)b * NN + blockIdx.x * 64 + threadIdx.x] = t;
    }
}

// ---------------------------------------------------------------------------
// pv: XR[b,c,m] = (sum_n V[b,c,n] * S[b,n,m]) / (1e-7 + colsum[b,m])
// ---------------------------------------------------------------------------
__global__ __launch_bounds__(256) void pv_kernel(
    const float* __restrict__ V,       // [B,C,N]
    const u16* __restrict__ S,         // [B,N,N] bf16
    const float* __restrict__ colsum,  // [B,N]
    float* __restrict__ XR)            // [B,C,N]
{
    const int b   = blockIdx.z;
    const int c0  = blockIdx.y * 64;
    const int m0  = blockIdx.x * 64;
    const int tid = threadIdx.x;
    const int ty  = tid >> 4, tx = tid & 15;

    __shared__ float Vs[32][68];   // Vs[kk][c]
    __shared__ float Ss[32][68];   // Ss[kk][m]

    float acc[4][4] = {};
    const float* Vb = V + (size_t)b * CN;
    const u16*   Sb = S + (size_t)b * NN * NN;

    for (int k0 = 0; k0 < NN; k0 += 32) {
        {   // V tile (transposed into [kk][c])
            const int c  = tid >> 2;
            const int n8 = (tid & 3) * 8;
            const size_t base = (size_t)(c0 + c) * NN + k0 + n8;
            const float4 v0 = *(const float4*)&Vb[base];
            const float4 v1 = *(const float4*)&Vb[base + 4];
            Vs[n8 + 0][c] = v0.x; Vs[n8 + 1][c] = v0.y; Vs[n8 + 2][c] = v0.z; Vs[n8 + 3][c] = v0.w;
            Vs[n8 + 4][c] = v1.x; Vs[n8 + 5][c] = v1.y; Vs[n8 + 6][c] = v1.z; Vs[n8 + 7][c] = v1.w;
        }
        {   // S tile (bf16 -> fp32)
            const int kk = tid >> 3;
            const int m8 = (tid & 7) * 8;
            const uint4 sv = *(const uint4*)(const void*)&Sb[(size_t)(k0 + kk) * NN + m0 + m8];
            const unsigned int uu[4] = { sv.x, sv.y, sv.z, sv.w };
            #pragma unroll
            for (int q = 0; q < 4; q++) {
                Ss[kk][m8 + 2 * q]     = bf2f((u16)(uu[q] & 0xffffu));
                Ss[kk][m8 + 2 * q + 1] = bf2f((u16)(uu[q] >> 16));
            }
        }
        __syncthreads();
        #pragma unroll 8
        for (int kk = 0; kk < 32; kk++) {
            float av[4], bv[4];
            *(float4*)av = *(const float4*)&Vs[kk][ty * 4];
            *(float4*)bv = *(const float4*)&Ss[kk][tx * 4];
            #pragma unroll
            for (int i = 0; i < 4; i++)
                #pragma unroll
                for (int j = 0; j < 4; j++)
                    acc[i][j] = fmaf(av[i], bv[j], acc[i][j]);
        }
        __syncthreads();
    }

    float inv[4];
    #pragma unroll
    for (int j = 0; j < 4; j++)
        inv[j] = 1.0f / (1e-7f + colsum[(size_t)b * NN + m0 + tx * 4 + j]);
    #pragma unroll
    for (int i = 0; i < 4; i++) {
        float4 o;
        o.x = acc[i][0] * inv[0]; o.y = acc[i][1] * inv[1];
        o.z = acc[i][2] * inv[2]; o.w = acc[i][3] * inv[3];
        *(float4*)&XR[((size_t)b * CC + c0 + ty * 4 + i) * NN + m0 + tx * 4] = o;
    }
}

// ---------------------------------------------------------------------------
// elementwise combines
// ---------------------------------------------------------------------------
__global__ __launch_bounds__(256) void ew_update_kernel(float* __restrict__ A,
                                                        const float* __restrict__ Bv)
{
    const size_t i = ((size_t)blockIdx.x * 256 + threadIdx.x) * 4;
    float4 a = *(float4*)&A[i];
    const float4 b = *(const float4*)&Bv[i];
    a.x = tanhf(a.x * sigf(b.x));
    a.y = tanhf(a.y * sigf(b.y));
    a.z = tanhf(a.z * sigf(b.z));
    a.w = tanhf(a.w * sigf(b.w));
    *(float4*)&A[i] = a;
}

__global__ __launch_bounds__(256) void ew_final_kernel(const float* __restrict__ TU,
                                                       const float* __restrict__ SU,
                                                       const float* __restrict__ x,
                                                       float* __restrict__ OUT)
{
    const size_t i   = ((size_t)blockIdx.x * 256 + threadIdx.x) * 4;
    const size_t b   = i / CN;
    const size_t off = i - b * CN;
    const float4 mid = *(const float4*)&x[(b * 3 + 1) * CN + off];
    const float4 g   = *(const float4*)&OUT[i];
    const float4 tu  = *(const float4*)&TU[i];
    const float4 su  = *(const float4*)&SU[i];
    float4 o;
    o.x = mid.x + sigf((tu.x + su.x) * sigf(g.x)) * tanhf(g.x);
    o.y = mid.y + sigf((tu.y + su.y) * sigf(g.y)) * tanhf(g.y);
    o.z = mid.z + sigf((tu.z + su.z) * sigf(g.z)) * tanhf(g.z);
    o.w = mid.w + sigf((tu.w + su.w) * sigf(g.w)) * tanhf(g.w);
    *(float4*)&OUT[i] = o;
}

// ---------------------------------------------------------------------------
extern "C" void kernel_launch(void* const* d_in, const int* in_sizes, int n_in,
                              void* d_out, int out_size, void* d_ws, size_t ws_size,
                              hipStream_t stream)
{
    const float* x   = (const float*)d_in[0];
    const float* Wqk = (const float*)d_in[1];
    const float* Vw  = (const float*)d_in[2];
    const float* Vb  = (const float*)d_in[3];
    const float* Tw  = (const float*)d_in[4];
    const float* Tb  = (const float*)d_in[5];
    float* out = (float*)d_out;

    char* ws = (char*)d_ws;
    const size_t SZ = (size_t)BB * CN * sizeof(float);           // 16 MiB
    const size_t need = 6 * SZ + (1u << 20) + (size_t)BB * NN * NN * 2;
    if (ws_size < need) return;  // ws too small: leave output poisoned (signals restructure)

    float* Kb   = (float*)(ws);
    float* Qb   = (float*)(ws + SZ);
    float* Vbuf = (float*)(ws + 2 * SZ);
    float* XRb  = (float*)(ws + 3 * SZ);   // doubles as cspart then XR
    float* Oa   = (float*)(ws + 4 * SZ);
    float* Ob   = (float*)(ws + 5 * SZ);
    float* csum = (float*)(ws + 6 * SZ);
    u16*   Sb   = (u16*)(ws + 6 * SZ + (1u << 20));

    const dim3 convGrid(NN / 64, CC / 64, BB);
    const dim3 attnGrid(NN / 8, BB);
    const dim3 pvGrid(NN / 64, CC / 64, BB);
    const dim3 csGrid(NN / 64, BB);

    auto run_mod = [&](int i, int xs, int ys, float* O) {
        const float* Wi = Wqk + (size_t)i * CC * CC;
        conv1x1_kernel<0><<<convGrid, 256, 0, stream>>>(Wi, x + (size_t)xs * CN, (long)XBS,
                                                        nullptr, nullptr, Kb, (long)CN);
        const float* Qp = Kb;
        if (ys != xs) {
            conv1x1_kernel<0><<<convGrid, 256, 0, stream>>>(Wi, x + (size_t)ys * CN, (long)XBS,
                                                            nullptr, nullptr, Qb, (long)CN);
            Qp = Qb;
        }
        conv1x1_kernel<1><<<convGrid, 256, 0, stream>>>(Vw + (size_t)i * CC * CC, x + (size_t)xs * CN,
                                                        (long)XBS, nullptr, Vb + (size_t)i * CC,
                                                        Vbuf, (long)CN);
        attn_kernel<<<attnGrid, 256, 0, stream>>>(Qp, Kb, Sb, XRb);
        csum_kernel<<<csGrid, 256, 0, stream>>>(XRb, csum);
        pv_kernel<<<pvGrid, 256, 0, stream>>>(Vbuf, Sb, csum, XRb);
        conv1x1_kernel<2><<<convGrid, 256, 0, stream>>>(Tw + (size_t)i * CC * CC, x + (size_t)xs * CN,
                                                        (long)XBS, XRb, Tb + (size_t)i * CC,
                                                        O, (long)CN);
    };

    // module -> (x-side slice, y-side slice): time=0, mid=1, space=2
    run_mod(0, 0, 0, Oa);                                   // time_att
    run_mod(2, 0, 2, Ob);                                   // time_cor
    ew_update_kernel<<<4096, 256, 0, stream>>>(Oa, Ob);     // Oa = time_update
    run_mod(1, 2, 2, Ob);                                   // space_att
    run_mod(3, 2, 0, out);                                  // space_cor (d_out as temp)
    ew_update_kernel<<<4096, 256, 0, stream>>>(Ob, out);    // Ob = space_update
    run_mod(4, 1, 1, out);                                  // global_feat -> d_out
    ew_final_kernel<<<4096, 256, 0, stream>>>(Oa, Ob, x, out);
}

// Round 2
// 1459.821 us; speedup vs baseline: 2.1053x; 2.1053x over previous
//
#include <hip/hip_runtime.h>
#include <math.h>

#define BB 8
#define CC 256
#define NN 2048

static const size_t CN  = (size_t)CC * NN;   // elements per [C,N] slab
static const size_t XBS = 3 * CN;            // batch stride of x [B,3,C,N]

typedef unsigned short u16;
typedef __attribute__((ext_vector_type(8))) short short8;   // 8 bf16 (one MFMA frag)
typedef __attribute__((ext_vector_type(4))) float f32x4;    // MFMA acc

__device__ __forceinline__ float bf2f(u16 v) {
    union { unsigned int u; float f; } t; t.u = ((unsigned int)v) << 16; return t.f;
}
__device__ __forceinline__ u16 f2bf(float f) {
    union { float f; unsigned int u; } t; t.f = f;
    return (u16)((t.u + 0x7fffu + ((t.u >> 16) & 1u)) >> 16);
}
__device__ __forceinline__ float sigf(float x) { return 1.0f / (1.0f + expf(-x)); }

// ---------------------------------------------------------------------------
// cast fp32 -> bf16 (weights)
// ---------------------------------------------------------------------------
__global__ __launch_bounds__(256) void cast_kernel(const float* __restrict__ in,
                                                   u16* __restrict__ out)
{
    const size_t i = ((size_t)blockIdx.x * 256 + threadIdx.x) * 4;
    const float4 v = *(const float4*)&in[i];
    ushort4 p;
    p.x = f2bf(v.x); p.y = f2bf(v.y); p.z = f2bf(v.z); p.w = f2bf(v.w);
    *(ushort4*)&out[i] = p;
}

// ---------------------------------------------------------------------------
// transpose-cast: out[n][c] = bf16(in[c][n] - (SUB ? sub[c][n] : 0))
// grid (NN/64, CC/64, Z); per-z strides in elements.
// ---------------------------------------------------------------------------
template<int SUB>
__global__ __launch_bounds__(256) void tcast_kernel(
    const float* __restrict__ in, long in_bs,
    const float* __restrict__ sub, long sub_bs,
    u16* __restrict__ out, long out_bs)
{
    const int z = blockIdx.z;
    const float* I = in + (size_t)z * in_bs;
    const float* S = SUB ? (sub + (size_t)z * sub_bs) : nullptr;
    u16* O = out + (size_t)z * out_bs;
    const int c0 = blockIdx.y * 64, n0 = blockIdx.x * 64;
    const int tx = threadIdx.x & 15, ty = threadIdx.x >> 4;

    __shared__ float t[64][68];

    #pragma unroll
    for (int cc = 0; cc < 64; cc += 16) {
        const int c = ty + cc;
        const size_t g = (size_t)(c0 + c) * NN + n0 + tx * 4;
        float4 v = *(const float4*)&I[g];
        if (SUB) {
            const float4 s = *(const float4*)&S[g];
            v.x -= s.x; v.y -= s.y; v.z -= s.z; v.w -= s.w;
        }
        *(float4*)&t[c][tx * 4] = v;
    }
    __syncthreads();
    #pragma unroll
    for (int nn2 = 0; nn2 < 64; nn2 += 16) {
        const int n = ty + nn2;
        ushort4 p;
        p.x = f2bf(t[tx * 4 + 0][n]);
        p.y = f2bf(t[tx * 4 + 1][n]);
        p.z = f2bf(t[tx * 4 + 2][n]);
        p.w = f2bf(t[tx * 4 + 3][n]);
        *(ushort4*)&O[(size_t)(n0 + n) * CC + c0 + tx * 4] = p;
    }
}

// ---------------------------------------------------------------------------
// conv1x1 via MFMA: D[c][n] = sum_k W[c][k] * X^T[n][k]   (per batch z)
// A = W bf16 [CC][CC] (k-contiguous rows), B = Xt bf16 [N][CC] (k-contiguous).
// Block 256 thr = 4 waves (2c x 2n), tile 128c x 128n, wave 64x64 (4x4 frags).
// MODE 0: out bf16 [N][C] (Q/K, transposed for attn)
// MODE 1: out bf16 [C][N] + bias (V)
// MODE 2: out fp32 [C][N] = xres + relu(acc + bias) (T stage)
// ---------------------------------------------------------------------------
template<int MODE>
__global__ __launch_bounds__(256) void conv_mfma(
    const u16* __restrict__ W,
    const u16* __restrict__ Xb, long xbs,
    const float* __restrict__ bias,
    const float* __restrict__ xres, long rbs,
    void* __restrict__ outv, long obs)
{
    const int b = blockIdx.z;
    const int n0 = blockIdx.x * 128, c0 = blockIdx.y * 128;
    const int lane = threadIdx.x & 63, wave = threadIdx.x >> 6;
    const int wc = (wave >> 1) * 64, wn = (wave & 1) * 64;
    const int l15 = lane & 15, lk = (lane >> 4) * 8;

    const u16* Xp = Xb + (size_t)b * xbs;
    f32x4 acc[4][4] = {};

    const u16* wrow[4]; const u16* xrow[4];
    #pragma unroll
    for (int ai = 0; ai < 4; ai++) wrow[ai] = W  + (size_t)(c0 + wc + ai * 16 + l15) * CC + lk;
    #pragma unroll
    for (int bj = 0; bj < 4; bj++) xrow[bj] = Xp + (size_t)(n0 + wn + bj * 16 + l15) * CC + lk;

    #pragma unroll 2
    for (int kc = 0; kc < 8; kc++) {
        short8 a[4], bf[4];
        #pragma unroll
        for (int ai = 0; ai < 4; ai++) a[ai]  = *(const short8*)(wrow[ai] + kc * 32);
        #pragma unroll
        for (int bj = 0; bj < 4; bj++) bf[bj] = *(const short8*)(xrow[bj] + kc * 32);
        #pragma unroll
        for (int ai = 0; ai < 4; ai++)
            #pragma unroll
            for (int bj = 0; bj < 4; bj++)
                acc[ai][bj] = __builtin_amdgcn_mfma_f32_16x16x32_bf16(a[ai], bf[bj], acc[ai][bj], 0, 0, 0);
    }

    if (MODE == 0) {
        u16* Ot = (u16*)outv + (size_t)b * obs;
        #pragma unroll
        for (int bj = 0; bj < 4; bj++) {
            const int n = n0 + wn + bj * 16 + l15;
            #pragma unroll
            for (int ai = 0; ai < 4; ai++) {
                const int cb = c0 + wc + ai * 16 + (lane >> 4) * 4;
                ushort4 p;
                p.x = f2bf(acc[ai][bj][0]); p.y = f2bf(acc[ai][bj][1]);
                p.z = f2bf(acc[ai][bj][2]); p.w = f2bf(acc[ai][bj][3]);
                *(ushort4*)&Ot[(size_t)n * CC + cb] = p;
            }
        }
    } else if (MODE == 1) {
        u16* Oc = (u16*)outv + (size_t)b * obs;
        #pragma unroll
        for (int ai = 0; ai < 4; ai++)
            #pragma unroll
            for (int r = 0; r < 4; r++) {
                const int c = c0 + wc + ai * 16 + (lane >> 4) * 4 + r;
                const float bi = bias[c];
                #pragma unroll
                for (int bj = 0; bj < 4; bj++) {
                    const int n = n0 + wn + bj * 16 + l15;
                    Oc[(size_t)c * NN + n] = f2bf(acc[ai][bj][r] + bi);
                }
            }
    } else {
        float* Of = (float*)outv + (size_t)b * obs;
        const float* Xr = xres + (size_t)b * rbs;
        #pragma unroll
        for (int ai = 0; ai < 4; ai++)
            #pragma unroll
            for (int r = 0; r < 4; r++) {
                const int c = c0 + wc + ai * 16 + (lane >> 4) * 4 + r;
                const float bi = bias[c];
                #pragma unroll
                for (int bj = 0; bj < 4; bj++) {
                    const int n = n0 + wn + bj * 16 + l15;
                    Of[(size_t)c * NN + n] = Xr[(size_t)c * NN + n] + fmaxf(acc[ai][bj][r] + bi, 0.0f);
                }
            }
    }
}

// ---------------------------------------------------------------------------
// attention: logits[n][m] = sum_c Qt[n][c]*Kt[m][c] via MFMA into LDS;
// row softmax; write S in blocked layout St[b][n>>3][m][n&7] (bf16) +
// per-block column partial sums. 512 thr = 8 waves; 16 rows/block.
// ---------------------------------------------------------------------------
__global__ __launch_bounds__(512) void attn_mfma(
    const u16* __restrict__ Qt,   // [B][N][C]
    const u16* __restrict__ Kt,   // [B][N][C]
    u16* __restrict__ St,         // [B][N/8][N][8]
    float* __restrict__ cspart)   // [B][N/16][N]
{
    const int b = blockIdx.y, n0 = blockIdx.x * 16;
    const int tid = threadIdx.x, lane = tid & 63, wave = tid >> 6;
    const int l15 = lane & 15, lk = (lane >> 4) * 8;

    __shared__ float L[16][NN];   // 128 KiB
    __shared__ float rs[16];

    short8 a[8];
    {
        const u16* q = Qt + ((size_t)b * NN + n0 + l15) * CC + lk;
        #pragma unroll
        for (int kc = 0; kc < 8; kc++) a[kc] = *(const short8*)(q + kc * 32);
    }

    for (int t = 0; t < 16; t++) {
        const int m0 = wave * 256 + t * 16;
        const u16* kr = Kt + ((size_t)b * NN + m0 + l15) * CC + lk;
        f32x4 acc = {};
        #pragma unroll
        for (int kc = 0; kc < 8; kc++) {
            const short8 bf = *(const short8*)(kr + kc * 32);
            acc = __builtin_amdgcn_mfma_f32_16x16x32_bf16(a[kc], bf, acc, 0, 0, 0);
        }
        const int rb = (lane >> 4) * 4, m = m0 + l15;
        #pragma unroll
        for (int r = 0; r < 4; r++) L[rb + r][m] = acc[r];
    }
    __syncthreads();

    // softmax: wave handles rows 2w, 2w+1
    #pragma unroll
    for (int rr = 0; rr < 2; rr++) {
        const int r = wave * 2 + rr;
        float mx = -1e30f;
        for (int k = 0; k < 32; k++) mx = fmaxf(mx, L[r][lane + k * 64]);
        #pragma unroll
        for (int o = 32; o; o >>= 1) mx = fmaxf(mx, __shfl_xor(mx, o));
        float sum = 0.0f;
        for (int k = 0; k < 32; k++) {
            const float e = expf(L[r][lane + k * 64] - mx);
            L[r][lane + k * 64] = e;
            sum += e;
        }
        #pragma unroll
        for (int o = 32; o; o >>= 1) sum += __shfl_xor(sum, o);
        if (lane == 0) rs[r] = 1.0f / sum;
    }
    __syncthreads();

    float rv[16];
    #pragma unroll
    for (int r = 0; r < 16; r++) rv[r] = rs[r];

    u16* sb = St + ((size_t)b * (NN / 8) + (n0 >> 3)) * (size_t)NN * 8;
    float* cp = cspart + ((size_t)b * (NN / 16) + blockIdx.x) * NN;

    for (int mm = 0; mm < 4; mm++) {
        const int m = tid + mm * 512;
        float cs = 0.0f;
        short8 lo, hi;
        #pragma unroll
        for (int r = 0; r < 8; r++) {
            const float v = L[r][m] * rv[r];
            lo[r] = (short)f2bf(v); cs += v;
        }
        #pragma unroll
        for (int r = 0; r < 8; r++) {
            const float v = L[r + 8][m] * rv[r + 8];
            hi[r] = (short)f2bf(v); cs += v;
        }
        *(short8*)&sb[(size_t)m * 8] = lo;
        *(short8*)&sb[(size_t)NN * 8 + (size_t)m * 8] = hi;
        cp[m] = cs;
    }
}

// ---------------------------------------------------------------------------
// colsum[b][m] = sum_g cspart[b][g][m], g < 128
// ---------------------------------------------------------------------------
__global__ __launch_bounds__(256) void csum_kernel(const float* __restrict__ cspart,
                                                   float* __restrict__ colsum)
{
    const int b  = blockIdx.y;
    const int ml = threadIdx.x & 63;
    const int m  = blockIdx.x * 64 + ml;
    const int g0 = threadIdx.x >> 6;
    float s = 0.0f;
    for (int g = g0; g < 128; g += 4)
        s += cspart[((size_t)b * 128 + g) * NN + m];
    __shared__ float red[4][64];
    red[g0][ml] = s;
    __syncthreads();
    if (threadIdx.x < 64) {
        colsum[(size_t)b * NN + blockIdx.x * 64 + threadIdx.x] =
            red[0][threadIdx.x] + red[1][threadIdx.x] +
            red[2][threadIdx.x] + red[3][threadIdx.x];
    }
}

// ---------------------------------------------------------------------------
// pv: XR[c][m] = (sum_n V[c][n] * S[n][m]) / (1e-7 + colsum[m])
// A = V bf16 [C][N] (n-contiguous), B = St blocked [g][m][8] (n-contiguous).
// Block 4 waves (2c x 2m), tile 128c x 64m; wave 64c x 32m (4x2 frags).
// ---------------------------------------------------------------------------
__global__ __launch_bounds__(256) void pv_mfma(
    const u16* __restrict__ V,        // [B][C][N]
    const u16* __restrict__ St,       // [B][N/8][N][8]
    const float* __restrict__ colsum, // [B][N]
    float* __restrict__ XR)           // [B][C][N]
{
    const int b = blockIdx.z, m0b = blockIdx.x * 64, c0 = blockIdx.y * 128;
    const int lane = threadIdx.x & 63, wave = threadIdx.x >> 6;
    const int wc = (wave >> 1) * 64, wm = (wave & 1) * 32;
    const int l15 = lane & 15, lg = lane >> 4;

    f32x4 acc[4][2] = {};
    const u16* vp[4]; const u16* sp[2];
    #pragma unroll
    for (int ai = 0; ai < 4; ai++)
        vp[ai] = V + ((size_t)b * CC + c0 + wc + ai * 16 + l15) * NN + lg * 8;
    #pragma unroll
    for (int bj = 0; bj < 2; bj++)
        sp[bj] = St + (((size_t)b * (NN / 8) + lg) * NN + m0b + wm + bj * 16 + l15) * 8;

    #pragma unroll 2
    for (int kc = 0; kc < 64; kc++) {
        short8 a[4], s2[2];
        #pragma unroll
        for (int ai = 0; ai < 4; ai++) { a[ai] = *(const short8*)vp[ai]; vp[ai] += 32; }
        #pragma unroll
        for (int bj = 0; bj < 2; bj++) { s2[bj] = *(const short8*)sp[bj]; sp[bj] += (size_t)4 * NN * 8; }
        #pragma unroll
        for (int ai = 0; ai < 4; ai++)
            #pragma unroll
            for (int bj = 0; bj < 2; bj++)
                acc[ai][bj] = __builtin_amdgcn_mfma_f32_16x16x32_bf16(a[ai], s2[bj], acc[ai][bj], 0, 0, 0);
    }

    #pragma unroll
    for (int bj = 0; bj < 2; bj++) {
        const int m = m0b + wm + bj * 16 + l15;
        const float inv = 1.0f / (1e-7f + colsum[(size_t)b * NN + m]);
        #pragma unroll
        for (int ai = 0; ai < 4; ai++) {
            const int cb = c0 + wc + ai * 16 + lg * 4;
            #pragma unroll
            for (int r = 0; r < 4; r++)
                XR[((size_t)b * CC + cb + r) * NN + m] = acc[ai][bj][r] * inv;
        }
    }
}

// ---------------------------------------------------------------------------
// elementwise combines (unchanged from round 1)
// ---------------------------------------------------------------------------
__global__ __launch_bounds__(256) void ew_update_kernel(float* __restrict__ A,
                                                        const float* __restrict__ Bv)
{
    const size_t i = ((size_t)blockIdx.x * 256 + threadIdx.x) * 4;
    float4 a = *(float4*)&A[i];
    const float4 b = *(const float4*)&Bv[i];
    a.x = tanhf(a.x * sigf(b.x));
    a.y = tanhf(a.y * sigf(b.y));
    a.z = tanhf(a.z * sigf(b.z));
    a.w = tanhf(a.w * sigf(b.w));
    *(float4*)&A[i] = a;
}

__global__ __launch_bounds__(256) void ew_final_kernel(const float* __restrict__ TU,
                                                       const float* __restrict__ SU,
                                                       const float* __restrict__ x,
                                                       float* __restrict__ OUT)
{
    const size_t i   = ((size_t)blockIdx.x * 256 + threadIdx.x) * 4;
    const size_t b   = i / CN;
    const size_t off = i - b * CN;
    const float4 mid = *(const float4*)&x[(b * 3 + 1) * CN + off];
    const float4 g   = *(const float4*)&OUT[i];
    const float4 tu  = *(const float4*)&TU[i];
    const float4 su  = *(const float4*)&SU[i];
    float4 o;
    o.x = mid.x + sigf((tu.x + su.x) * sigf(g.x)) * tanhf(g.x);
    o.y = mid.y + sigf((tu.y + su.y) * sigf(g.y)) * tanhf(g.y);
    o.z = mid.z + sigf((tu.z + su.z) * sigf(g.z)) * tanhf(g.z);
    o.w = mid.w + sigf((tu.w + su.w) * sigf(g.w)) * tanhf(g.w);
    *(float4*)&OUT[i] = o;
}

// ---------------------------------------------------------------------------
extern "C" void kernel_launch(void* const* d_in, const int* in_sizes, int n_in,
                              void* d_out, int out_size, void* d_ws, size_t ws_size,
                              hipStream_t stream)
{
    const float* x   = (const float*)d_in[0];
    const float* Wqk = (const float*)d_in[1];
    const float* Vw  = (const float*)d_in[2];
    const float* Vb  = (const float*)d_in[3];
    const float* Tw  = (const float*)d_in[4];
    const float* Tb  = (const float*)d_in[5];
    float* out = (float*)d_out;

    char* ws = (char*)d_ws;
    size_t off = 0;
    auto alloc = [&](size_t bytes) { void* p = ws + off; off += (bytes + 255) & ~255ULL; return p; };

    const size_t SLAB16 = (size_t)NN * CC * 2;       // one bf16 [N][C] slab
    u16*   Xt     = (u16*)  alloc((size_t)BB * 3 * NN * CC * 2);  // 24 MiB
    u16*   W16    = (u16*)  alloc((size_t)3 * 5 * CC * CC * 2);
    u16*   Qt     = (u16*)  alloc((size_t)BB * SLAB16);
    u16*   Kt     = (u16*)  alloc((size_t)BB * SLAB16);
    u16*   V16    = (u16*)  alloc((size_t)BB * SLAB16);
    u16*   Dt     = (u16*)  alloc((size_t)BB * SLAB16);
    u16*   Sblk   = (u16*)  alloc((size_t)BB * NN * NN * 2);      // 64 MiB
    float* cspart = (float*)alloc((size_t)BB * 128 * NN * 4);
    float* csumb  = (float*)alloc((size_t)BB * NN * 4);
    float* XRb    = (float*)alloc((size_t)BB * CN * 4);
    float* Oa     = (float*)alloc((size_t)BB * CN * 4);
    float* Ob     = (float*)alloc((size_t)BB * CN * 4);
    (void)alloc(4096);   // tail slack
    if (ws_size < off) return;

    // weights -> bf16
    cast_kernel<<<320, 256, 0, stream>>>(Wqk, W16);
    cast_kernel<<<320, 256, 0, stream>>>(Vw,  W16 + 5 * CC * CC);
    cast_kernel<<<320, 256, 0, stream>>>(Tw,  W16 + 10 * CC * CC);
    // x -> Xt bf16 [B*3][N][C]
    tcast_kernel<0><<<dim3(NN / 64, CC / 64, BB * 3), 256, 0, stream>>>(
        x, (long)CN, nullptr, 0, Xt, (long)(NN * CC));

    const dim3 convGrid(NN / 128, CC / 128, BB);
    const dim3 attnGrid(NN / 16, BB);
    const dim3 csGrid(NN / 64, BB);
    const dim3 pvGrid(NN / 64, CC / 128, BB);
    const dim3 tGrid(NN / 64, CC / 64, BB);
    const long XT_BS = (long)(3 * NN * CC);
    const long NC    = (long)(NN * CC);

    auto run_mod = [&](int i, int xs, int ys, float* O) {
        const u16* Wi = W16 + (size_t)i * CC * CC;
        const u16* Wv = W16 + (size_t)(5 + i) * CC * CC;
        const u16* Wt = W16 + (size_t)(10 + i) * CC * CC;
        conv_mfma<0><<<convGrid, 256, 0, stream>>>(Wi, Xt + (size_t)xs * NN * CC, XT_BS,
                                                   nullptr, nullptr, 0, Kt, NC);
        const u16* Qp = Kt;
        if (ys != xs) {
            conv_mfma<0><<<convGrid, 256, 0, stream>>>(Wi, Xt + (size_t)ys * NN * CC, XT_BS,
                                                       nullptr, nullptr, 0, Qt, NC);
            Qp = Qt;
        }
        conv_mfma<1><<<convGrid, 256, 0, stream>>>(Wv, Xt + (size_t)xs * NN * CC, XT_BS,
                                                   Vb + (size_t)i * CC, nullptr, 0, V16, (long)CN);
        attn_mfma<<<attnGrid, 512, 0, stream>>>(Qp, Kt, Sblk, cspart);
        csum_kernel<<<csGrid, 256, 0, stream>>>(cspart, csumb);
        pv_mfma<<<pvGrid, 256, 0, stream>>>(V16, Sblk, csumb, XRb);
        tcast_kernel<1><<<tGrid, 256, 0, stream>>>(x + (size_t)xs * CN, (long)XBS,
                                                   XRb, (long)CN, Dt, NC);
        conv_mfma<2><<<convGrid, 256, 0, stream>>>(Wt, Dt, NC, Tb + (size_t)i * CC,
                                                   x + (size_t)xs * CN, (long)XBS, O, (long)CN);
    };

    // module -> (x-side slice, y-side slice): time=0, mid=1, space=2
    run_mod(0, 0, 0, Oa);                                   // time_att
    run_mod(2, 0, 2, Ob);                                   // time_cor
    ew_update_kernel<<<4096, 256, 0, stream>>>(Oa, Ob);     // Oa = time_update
    run_mod(1, 2, 2, Ob);                                   // space_att
    run_mod(3, 2, 0, out);                                  // space_cor (d_out as temp)
    ew_update_kernel<<<4096, 256, 0, stream>>>(Ob, out);    // Ob = space_update
    run_mod(4, 1, 1, out);                                  // global_feat -> d_out
    ew_final_kernel<<<4096, 256, 0, stream>>>(Oa, Ob, x, out);
}